// Round 4
// baseline (31.342 us; speedup 1.0000x reference)
//
#include <hip/hip_runtime.h>
#include <math.h>

// out[b, 0:1024]    = -0.5*z^2 - log(std) - 0.5*log(2pi),  z=(x[b,gsc[g]]-mean[g])/std[g]
// out[b, 1024:2048] = cat_logp[c, (int)x[b, csc[c]]]
// B=16384, x:[B,256] f32, NG=NC=1024, K=32.
//
// Design B + software pipeline:
//  - gather-transposed cat half (lanes = rows): <=8 cache lines per gather instr
//  - double-buffered cat LDS tile: per chunk {gather -> flush prev -> write -> 1 sync}
//  - chunk-0 gathers issued BEFORE the gaussian phase so gaussian VALU+stores
//    hide the first gather's latency

#define HALF_LOG_2PI 0.91893853320467274178f

constexpr int BROWS   = 16384;
constexpr int FX      = 256;
constexpr int NG      = 1024;
constexpr int NC      = 1024;
constexpr int KCAT    = 32;
constexpr int OUTW    = NG + NC;   // 2048
constexpr int ROWS_PB = 16;
constexpr int NTHR    = 256;
constexpr int XPITCH  = FX + 1;    // 257: read bank = (row + col) % 32 -> spread
constexpr int CCH     = 128;       // cat cols per chunk
constexpr int NCHUNK  = NC / CCH;  // 8
constexpr int CPITCH  = CCH + 4;   // 132: tile bank = (4*row + off) % 32 -> 2-way max

__global__ __launch_bounds__(NTHR) void leaves_kernel(
    const float* __restrict__ x,       // [B, 256]
    const float* __restrict__ gmean,   // [1024]
    const float* __restrict__ gstd,    // [1024]
    const float* __restrict__ clogp,   // [1024, 32]
    const int*   __restrict__ gsc,     // [1024] in [0,128)
    const int*   __restrict__ csc,     // [1024] in [128,256)
    float*       __restrict__ out)     // [B, 2048]
{
    __shared__ float xs[ROWS_PB * XPITCH];        // 16448 B
    __shared__ float cts[2][ROWS_PB * CPITCH];    // 2 x 8448 B

    const int t = threadIdx.x;
    const long long b0 = (long long)blockIdx.x * ROWS_PB;

    // ---- stage 16 x-rows: thread t loads row t>>4, cols (t&15)*16..+15 ----
    {
        const int r  = t >> 4;
        const int c0 = (t & 15) * 16;
        const float* src = x + (b0 + r) * FX + c0;
        float*       dst = xs + r * XPITCH + c0;
        #pragma unroll
        for (int q = 0; q < 4; ++q) {
            float4 v = ((const float4*)src)[q];
            dst[q * 4 + 0] = v.x; dst[q * 4 + 1] = v.y;
            dst[q * 4 + 2] = v.z; dst[q * 4 + 3] = v.w;
        }
    }

    // ---- per-thread gaussian tables (thread owns g-cols 4t..4t+3) ----
    const int4   g4 = ((const int4*)gsc)[t];
    const float4 mu = ((const float4*)gmean)[t];
    const float4 sd = ((const float4*)gstd)[t];
    float4 is, cc;
    is.x = 1.0f / sd.x;  cc.x = -logf(sd.x) - HALF_LOG_2PI;
    is.y = 1.0f / sd.y;  cc.y = -logf(sd.y) - HALF_LOG_2PI;
    is.z = 1.0f / sd.z;  cc.z = -logf(sd.z) - HALF_LOG_2PI;
    is.w = 1.0f / sd.w;  cc.w = -logf(sd.w) - HALF_LOG_2PI;

    __syncthreads();

    // cat-phase lane mapping: lanes = rows
    const int w   = t >> 6;        // wave 0..3
    const int l   = t & 63;
    const int row = l & 15;        // lane's row
    const int co  = l >> 4;        // 0..3: c sub-offset
    const float* xrp = xs + row * XPITCH;

    // flush mapping: thread t writes row t>>4, floats (t&15)*4 (+0 / +64)
    const int wr = t >> 4;
    const int wo = (t & 15) * 4;

    // ---- prologue: issue chunk-0 gathers (in flight during gaussian) ----
    float v[8];
    {
        const int cb = 0 * CCH + w * 32 + co;
        #pragma unroll
        for (int j = 0; j < 8; ++j) {
            const int c = cb + j * 4;
            v[j] = clogp[c * KCAT + (int)xrp[csc[c]]];
        }
    }

    // ---- Gaussian half: 16 rows, coalesced 1KB wave stores ----
    #pragma unroll
    for (int r = 0; r < ROWS_PB; ++r) {
        const float* xr = xs + r * XPITCH;
        float4 gres;
        { float z = (xr[g4.x] - mu.x) * is.x; gres.x = fmaf(-0.5f * z, z, cc.x); }
        { float z = (xr[g4.y] - mu.y) * is.y; gres.y = fmaf(-0.5f * z, z, cc.y); }
        { float z = (xr[g4.z] - mu.z) * is.z; gres.z = fmaf(-0.5f * z, z, cc.z); }
        { float z = (xr[g4.w] - mu.w) * is.w; gres.w = fmaf(-0.5f * z, z, cc.w); }
        ((float4*)(out + (b0 + r) * OUTW))[t] = gres;
    }

    // write chunk-0 results to tile 0
    #pragma unroll
    for (int j = 0; j < 8; ++j)
        cts[0][row * CPITCH + w * 32 + j * 4 + co] = v[j];
    __syncthreads();

    // ---- pipelined chunks 1..7: gather(k) || flush(k-1), then write(k), sync ----
    for (int chunk = 1; chunk < NCHUNK; ++chunk) {
        const int p  = chunk & 1;
        const int cb = chunk * CCH + w * 32 + co;

        // issue this chunk's gathers
        #pragma unroll
        for (int j = 0; j < 8; ++j) {
            const int c = cb + j * 4;
            v[j] = clogp[c * KCAT + (int)xrp[csc[c]]];
        }

        // flush previous chunk's tile (overlaps the in-flight gathers)
        {
            const float* src = cts[p ^ 1] + wr * CPITCH;
            float4 a = *(const float4*)(src + wo);
            float4 b = *(const float4*)(src + wo + 64);
            float* dst = out + (b0 + wr) * OUTW + NG + (chunk - 1) * CCH;
            *(float4*)(dst + wo)      = a;
            *(float4*)(dst + wo + 64) = b;
        }

        // write this chunk's results
        #pragma unroll
        for (int j = 0; j < 8; ++j)
            cts[p][row * CPITCH + w * 32 + j * 4 + co] = v[j];

        __syncthreads();
        // note: flush of tile p^1 completed before this barrier in every wave,
        // so next iteration's write to p^1 is safe with a single sync per chunk.
    }

    // ---- epilogue: flush last tile ----
    {
        const float* src = cts[(NCHUNK - 1) & 1] + wr * CPITCH;
        float4 a = *(const float4*)(src + wo);
        float4 b = *(const float4*)(src + wo + 64);
        float* dst = out + (b0 + wr) * OUTW + NG + (NCHUNK - 1) * CCH;
        *(float4*)(dst + wo)      = a;
        *(float4*)(dst + wo + 64) = b;
    }
}

extern "C" void kernel_launch(void* const* d_in, const int* in_sizes, int n_in,
                              void* d_out, int out_size, void* d_ws, size_t ws_size,
                              hipStream_t stream) {
    const float* x     = (const float*)d_in[0];
    const float* gmean = (const float*)d_in[1];
    const float* gstd  = (const float*)d_in[2];
    const float* clogp = (const float*)d_in[3];
    const int*   gsc   = (const int*)d_in[4];
    const int*   csc   = (const int*)d_in[5];
    float*       out   = (float*)d_out;

    leaves_kernel<<<dim3(BROWS / ROWS_PB), dim3(NTHR), 0, stream>>>(
        x, gmean, gstd, clogp, gsc, csc, out);
}

// Round 5
// 30.809 us; speedup vs baseline: 1.0173x; 1.0173x over previous
//
#include <hip/hip_runtime.h>
#include <math.h>

// out[b, 0:1024]    = -0.5*z^2 - log(std) - 0.5*log(2pi),  z=(x[b,gsc[g]]-mean[g])/std[g]
// out[b, 1024:2048] = cat_logp[c, (int)x[b, csc[c]]]
// B=16384, x:[B,256] f32, NG=NC=1024, K=32.
//
// Design C: barrier-free cat phase.
//  - gather-transposed (lanes = rows): one gather instr touches 4 consecutive
//    c's x 128B table blocks = ~8 cache lines (512B contiguous window).
//  - each wave's gathered data (16 rows x 32 c) is exactly what it must store
//    -> wave-PRIVATE LDS transpose tile, ordered by the wave's own lgkmcnt.
//    Zero __syncthreads in the whole cat phase; waves fully decoupled.
//  - flush mapping puts one full 64B line per row per store instruction.
//  - LDS 25.7 KB/block -> 6 blocks/CU (75% occupancy).

#define HALF_LOG_2PI 0.91893853320467274178f

constexpr int BROWS   = 16384;
constexpr int FX      = 256;
constexpr int NG      = 1024;
constexpr int NC      = 1024;
constexpr int KCAT    = 32;
constexpr int OUTW    = NG + NC;   // 2048
constexpr int ROWS_PB = 16;
constexpr int NTHR    = 256;
constexpr int XPITCH  = FX + 1;    // 257: cat idx-read bank = (row + col)%32 -> spread
constexpr int CCH     = 128;       // cat cols per chunk (32 per wave)
constexpr int NCHUNK  = NC / CCH;  // 8
constexpr int TPITCH  = 36;        // wave tile pitch: 16B-aligned rows, 2-way max on write

__global__ __launch_bounds__(NTHR) void leaves_kernel(
    const float* __restrict__ x,       // [B, 256]
    const float* __restrict__ gmean,   // [1024]
    const float* __restrict__ gstd,    // [1024]
    const float* __restrict__ clogp,   // [1024, 32]
    const int*   __restrict__ gsc,     // [1024] in [0,128)
    const int*   __restrict__ csc,     // [1024] in [128,256)
    float*       __restrict__ out)     // [B, 2048]
{
    __shared__ float xs[ROWS_PB * XPITCH];            // 16448 B
    __shared__ float wt[4][ROWS_PB * TPITCH];         //  9216 B (wave-private tiles)

    const int t = threadIdx.x;
    const long long b0 = (long long)blockIdx.x * ROWS_PB;

    // ---- stage 16 x-rows: thread t loads row t>>4, cols (t&15)*16..+15 ----
    {
        const int r  = t >> 4;
        const int c0 = (t & 15) * 16;
        const float* src = x + (b0 + r) * FX + c0;
        float*       dst = xs + r * XPITCH + c0;
        #pragma unroll
        for (int q = 0; q < 4; ++q) {
            float4 v = ((const float4*)src)[q];
            dst[q * 4 + 0] = v.x; dst[q * 4 + 1] = v.y;
            dst[q * 4 + 2] = v.z; dst[q * 4 + 3] = v.w;
        }
    }

    // ---- per-thread gaussian tables (thread owns g-cols 4t..4t+3) ----
    const int4   g4 = ((const int4*)gsc)[t];
    const float4 mu = ((const float4*)gmean)[t];
    const float4 sd = ((const float4*)gstd)[t];
    float4 is, cc;
    is.x = 1.0f / sd.x;  cc.x = -logf(sd.x) - HALF_LOG_2PI;
    is.y = 1.0f / sd.y;  cc.y = -logf(sd.y) - HALF_LOG_2PI;
    is.z = 1.0f / sd.z;  cc.z = -logf(sd.z) - HALF_LOG_2PI;
    is.w = 1.0f / sd.w;  cc.w = -logf(sd.w) - HALF_LOG_2PI;

    __syncthreads();   // the ONLY block-wide barrier

    // ---- Gaussian half: 16 rows, coalesced 1KB wave stores ----
    #pragma unroll
    for (int r = 0; r < ROWS_PB; ++r) {
        const float* xr = xs + r * XPITCH;
        float4 gres;
        { float z = (xr[g4.x] - mu.x) * is.x; gres.x = fmaf(-0.5f * z, z, cc.x); }
        { float z = (xr[g4.y] - mu.y) * is.y; gres.y = fmaf(-0.5f * z, z, cc.y); }
        { float z = (xr[g4.z] - mu.z) * is.z; gres.z = fmaf(-0.5f * z, z, cc.z); }
        { float z = (xr[g4.w] - mu.w) * is.w; gres.w = fmaf(-0.5f * z, z, cc.w); }
        ((float4*)(out + (b0 + r) * OUTW))[t] = gres;
    }

    // ---- Cat half: fully wave-local, no barriers ----
    const int w    = t >> 6;
    const int l    = t & 63;
    const int grow = l & 15;          // gather mapping: lane's row
    const int gco  = l >> 4;          // 0..3: c sub-offset
    const int frow = l >> 2;          // flush mapping: lane's row
    const int fol  = l & 3;           // 0..3: which 16B of the 64B line
    float*       tile = wt[w];
    const float* xrp  = xs + grow * XPITCH;

    for (int chunk = 0; chunk < NCHUNK; ++chunk) {
        const int cb = chunk * CCH + w * 32 + gco;   // this thread's c = cb + 4j

        // gather 8 values (32 c's per wave, 512B contiguous table window per j)
        float v[8];
        #pragma unroll
        for (int j = 0; j < 8; ++j) {
            const int c = cb + j * 4;
            v[j] = clogp[c * KCAT + (int)xrp[csc[c]]];
        }

        // in-wave transpose: write (2-way max bank overlap = free)
        #pragma unroll
        for (int j = 0; j < 8; ++j)
            tile[grow * TPITCH + j * 4 + gco] = v[j];

        // read back + store: per store-instr, each of 16 rows gets 1 full 64B line
        const float* trow = tile + frow * TPITCH;
        float*       drow = out + (b0 + frow) * OUTW + NG + chunk * CCH + w * 32;
        #pragma unroll
        for (int q = 0; q < 2; ++q) {
            float4 a = *(const float4*)(trow + q * 16 + fol * 4);
            *(float4*)(drow + q * 16 + fol * 4) = a;
        }
        // next chunk's tile writes are ordered after these reads by the wave's
        // own lgkmcnt dependencies -- no cross-wave hazard exists.
    }
}

extern "C" void kernel_launch(void* const* d_in, const int* in_sizes, int n_in,
                              void* d_out, int out_size, void* d_ws, size_t ws_size,
                              hipStream_t stream) {
    const float* x     = (const float*)d_in[0];
    const float* gmean = (const float*)d_in[1];
    const float* gstd  = (const float*)d_in[2];
    const float* clogp = (const float*)d_in[3];
    const int*   gsc   = (const int*)d_in[4];
    const int*   csc   = (const int*)d_in[5];
    float*       out   = (float*)d_out;

    leaves_kernel<<<dim3(BROWS / ROWS_PB), dim3(NTHR), 0, stream>>>(
        x, gmean, gstd, clogp, gsc, csc, out);
}